// Round 6
// baseline (2185.722 us; speedup 1.0000x reference)
//
#include <hip/hip_runtime.h>
#include <cstdint>

#define NPAT 8192
#define NBITS 4096

typedef float f32x2 __attribute__((ext_vector_type(2)));
typedef unsigned int u32;

// ws layout:
//   [0, 4 MiB)      : Bt[i][t] delta-sign bits, uint32, i in [0,4096), t in [0,256)
//                     thread t: b = t>>2, a = t&3
//                     bit (2k)   : sign of d for elem p = 128b + 2a     + 8k   (lo)
//                     bit (2k+1) : sign of d for elem p = 128b + 2a + 1 + 8k   (hi)
//                     where d = -2*state[i]*W[p][i]  (state = ORIGINAL state; valid
//                     because perm visits each i exactly once). sign bit set => d<0.
//   [4 MiB, +32 KiB): h0 float[8192] (exact integers)

__global__ void pack_kernel(const float* __restrict__ W, const float* __restrict__ state,
                            uint32_t* __restrict__ Bt) {
    int b = blockIdx.x & 63;
    int i = (blockIdx.x >> 6) * 256 + threadIdx.x;
    uint32_t spre = (__float_as_uint(state[i]) >> 31) ^ 1u;
    uint32_t wd0 = 0, wd1 = 0, wd2 = 0, wd3 = 0;
    const float* base = W + (size_t)(128 * b) * NBITS + i;
    #pragma unroll
    for (int q = 0; q < 128; ++q) {
        uint32_t bit = (__float_as_uint(base[(size_t)q * NBITS]) >> 31) ^ spre;  // coalesced
        int j = q & 7, k = q >> 3;
        int a = j >> 1, hi = j & 1;
        uint32_t add = bit << (2 * k + hi);
        if (a == 0) wd0 |= add;
        else if (a == 1) wd1 |= add;
        else if (a == 2) wd2 |= add;
        else wd3 |= add;
    }
    *(uint4*)(Bt + (size_t)i * 256 + 4 * b) = make_uint4(wd0, wd1, wd2, wd3);
}

__global__ void gemv_kernel(const float* __restrict__ W, const float* __restrict__ state,
                            float* __restrict__ h0) {
    int wid = threadIdx.x >> 6, lane = threadIdx.x & 63;
    int p = blockIdx.x * 4 + wid;
    const float* row = W + (size_t)p * NBITS;
    float acc = 0.f;
    for (int k = lane; k < NBITS; k += 64) acc += row[k] * state[k];
    #pragma unroll
    for (int d = 1; d < 64; d <<= 1) acc += __shfl_xor(acc, d, 64);
    if (lane == 0) h0[p] = acc;
}

// Exact numpy-pairwise tree (mapping proven bit-exact in R1-R5, absmax 0).
__device__ __forceinline__ float tree_reduce(float x) {
    x = __uint_as_float(__builtin_amdgcn_update_dpp(__float_as_uint(x), __float_as_uint(x),
                                                    0xB1, 0xf, 0xf, false)) + x;   // quad xor1
    x = __uint_as_float(__builtin_amdgcn_update_dpp(__float_as_uint(x), __float_as_uint(x),
                                                    0x4E, 0xf, 0xf, false)) + x;   // quad xor2
    x = __uint_as_float(__builtin_amdgcn_update_dpp(__float_as_uint(x), __float_as_uint(x),
                                                    0x141, 0xf, 0xf, false)) + x;  // b^1
    x = __uint_as_float(__builtin_amdgcn_update_dpp(__float_as_uint(x), __float_as_uint(x),
                                                    0x140, 0xf, 0xf, false)) + x;  // b^2
#if __has_builtin(__builtin_amdgcn_permlane16_swap)
    {
        auto pr = __builtin_amdgcn_permlane16_swap(__float_as_uint(x), __float_as_uint(x),
                                                   false, false);
        x = __uint_as_float(pr[0]) + __uint_as_float(pr[1]);                        // lane^16
    }
#else
    x = __int_as_float(__builtin_amdgcn_ds_swizzle(__float_as_int(x), 0x401F)) + x;
#endif
#if __has_builtin(__builtin_amdgcn_permlane32_swap)
    {
        auto pr = __builtin_amdgcn_permlane32_swap(__float_as_uint(x), __float_as_uint(x),
                                                   false, false);
        x = __uint_as_float(pr[0]) + __uint_as_float(pr[1]);                        // lane^32
    }
#else
    x += __shfl_xor(x, 32, 64);
#endif
    return x;
}

__device__ __forceinline__ f32x2 pkmax0(f32x2 v) {
    f32x2 z = {0.0f, 0.0f};
    return __builtin_elementwise_max(v, z);
}

// delta pair via 2-bit index -> 8B LDS table read (lands in an aligned VGPR pair)
#define GEN_DT(dst, w, tab)                                                   \
    _Pragma("unroll")                                                         \
    for (int k = 0; k < 16; ++k) {                                            \
        u32 _off = (k < 2) ? ((w << (3 - 2 * k)) & 0x18u)                     \
                           : ((w >> (2 * k - 3)) & 0x18u);                    \
        dst[k] = *(const f32x2*)((const char*)(tab) + _off);                  \
    }

__launch_bounds__(256, 1)
__global__ void seq_kernel(const uint32_t* __restrict__ Bt, const float* __restrict__ h0,
                           const float* __restrict__ state, const int* __restrict__ perm,
                           float* __restrict__ out) {
    __shared__ alignas(16) float part[2][4][4];   // [buf][wave][cand A,B,C,pad]
    __shared__ alignas(8)  f32x2 dtab[4];
    __shared__ int2 pv[NBITS];                    // (i, bits(state[i])) in visit order

    const int t = threadIdx.x;
    const int b = t >> 2, a = t & 3;
    const int lane = t & 63, wid = t >> 6;

    for (int q = t; q < NBITS; q += 256) {
        int ii = perm[q];
        pv[q] = make_int2(ii, __float_as_int(state[ii]));
    }
    if (t < 4) dtab[t] = (f32x2){(t & 1) ? -2.0f : 2.0f, (t & 2) ? -2.0f : 2.0f};

    f32x2 h[16];
    #pragma unroll
    for (int k = 0; k < 16; ++k) h[k] = *(const f32x2*)(h0 + 128 * b + 2 * a + 8 * k);

    __syncthreads();

    // Bt words for rounds 0..3 (steps 0..7); slot r&3 holds round r's pair
    u32 wA[4], wB[4];
    #pragma unroll
    for (int r = 0; r < 4; ++r) {
        wA[r] = Bt[(size_t)pv[2 * r].x * 256 + t];
        wB[r] = Bt[(size_t)pv[2 * r + 1].x * 256 + t];
    }

    f32x2 d0[2][16], d1[2][16];
    GEN_DT(d0[0], wA[0], dtab);        // round 0 deltas via LDS table
    GEN_DT(d1[0], wB[0], dtab);

    float Sprev;
    {   // S(h_0), numpy-exact
        f32x2 r;
        #pragma unroll
        for (int k = 0; k < 16; ++k) {
            f32x2 x = pkmax0(h[k]);
            r = (k == 0) ? x * x : __builtin_elementwise_fma(x, x, r);
        }
        float red = tree_reduce(r.x + r.y);
        if (lane == 0) part[0][wid][0] = red;
        asm volatile("s_waitcnt lgkmcnt(0)\n\ts_barrier" ::: "memory");
        float4 p0 = *(const float4*)(&part[0][0][0]);
        float4 p1 = *(const float4*)(&part[0][1][0]);
        float4 p2 = *(const float4*)(&part[0][2][0]);
        float4 p3 = *(const float4*)(&part[0][3][0]);
        Sprev = (p0.x + p1.x) + (p2.x + p3.x);
    }

    for (int rb = 0; rb < NBITS / 2; rb += 4) {
        #pragma unroll
        for (int u = 0; u < 4; ++u) {
            const int rr = rb + u;             // round = steps (2rr, 2rr+1)
            const int s  = 2 * rr;
            const int pb = u & 1;              // rb is a multiple of 4 -> rr&1 == u&1
            const int cu = u & 1;              // current d buffer

            // this round's (i0,v0,i1,v1) — ds_read_b128, consumed at decide
            int4 pvc = *(const int4*)(&pv[s]);

            // 3 candidate chains: A = h+d0, B = h+d1, C = (h+d0)+d1 (ref association)
            f32x2 ra, rbv, rc;
            #pragma unroll
            for (int k = 0; k < 16; ++k) {
                f32x2 va = h[k] + d0[cu][k];
                f32x2 vb = h[k] + d1[cu][k];
                f32x2 vc = va + d1[cu][k];
                f32x2 xa = pkmax0(va), xb = pkmax0(vb), xc = pkmax0(vc);
                if (k == 0) { ra = xa * xa; rbv = xb * xb; rc = xc * xc; }
                else {
                    ra  = __builtin_elementwise_fma(xa, xa, ra);
                    rbv = __builtin_elementwise_fma(xb, xb, rbv);
                    rc  = __builtin_elementwise_fma(xc, xc, rc);
                }
            }
            float Ra = tree_reduce(ra.x + ra.y);
            float Rb = tree_reduce(rbv.x + rbv.y);
            float Rc = tree_reduce(rc.x + rc.y);
            if (lane == 0)
                *(float4*)(&part[pb][wid][0]) = make_float4(Ra, Rb, Rc, 0.0f);  // one b128
            asm volatile("s_waitcnt lgkmcnt(0)\n\ts_barrier" ::: "memory");

            // post-barrier: issue part reads first (LDS FIFO -> earliest return) ...
            float4 p0 = *(const float4*)(&part[pb][0][0]);
            float4 p1 = *(const float4*)(&part[pb][1][0]);
            float4 p2 = *(const float4*)(&part[pb][2][0]);
            float4 p3 = *(const float4*)(&part[pb][3][0]);

            // ... then next round's delta-table reads (hide under decide+update)
            GEN_DT(d0[cu ^ 1], wA[(u + 1) & 3], dtab);
            GEN_DT(d1[cu ^ 1], wB[(u + 1) & 3], dtab);

            // ... and round rr+4's Bt words (4-round slack; slot u just freed)
            int li = (s + 8 < NBITS) ? s + 8 : NBITS - 2;   // even -> 16B aligned
            int4 pvn = *(const int4*)(&pv[li]);
            wA[u] = Bt[(size_t)pvn.x * 256 + t];
            wB[u] = Bt[(size_t)pvn.z * 256 + t];

            // decide (every thread redundantly; ties reject)
            float Sa = (p0.x + p1.x) + (p2.x + p3.x);
            float Sb = (p0.y + p1.y) + (p2.y + p3.y);
            float Sc = (p0.z + p1.z) + (p2.z + p3.z);
            bool acc0 = Sa > Sprev;
            bool acc1 = acc0 ? (Sc > Sa) : (Sb > Sprev);
            Sprev = acc1 ? (acc0 ? Sc : Sb) : (acc0 ? Sa : Sprev);

            if (t == 0) {
                float v0 = __int_as_float(pvc.y), v1 = __int_as_float(pvc.w);
                out[pvc.x] = acc0 ? -v0 : v0;
                out[pvc.z] = acc1 ? -v1 : v1;
            }

            float f0s = acc0 ? 1.0f : 0.0f, f1s = acc1 ? 1.0f : 0.0f;
            f32x2 f0 = {f0s, f0s}, f1 = {f1s, f1s};
            #pragma unroll
            for (int k = 0; k < 16; ++k) {     // exact: d*1=d, d*0=+/-0
                f32x2 hh = __builtin_elementwise_fma(d0[cu][k], f0, h[k]);
                h[k] = __builtin_elementwise_fma(d1[cu][k], f1, hh);
            }
        }
    }
}

extern "C" void kernel_launch(void* const* d_in, const int* in_sizes, int n_in,
                              void* d_out, int out_size, void* d_ws, size_t ws_size,
                              hipStream_t stream) {
    const float* W     = (const float*)d_in[0];
    const float* state = (const float*)d_in[1];
    const int*   perm  = (const int*)d_in[2];
    float*       out   = (float*)d_out;

    uint32_t* Bt = (uint32_t*)d_ws;
    float*    h0 = (float*)((char*)d_ws + (size_t)4096 * 256 * 4);

    pack_kernel<<<1024, 256, 0, stream>>>(W, state, Bt);
    gemv_kernel<<<2048, 256, 0, stream>>>(W, state, h0);
    seq_kernel<<<1, 256, 0, stream>>>(Bt, h0, state, perm, out);
}